// Round 1
// 1108.090 us; speedup vs baseline: 1.0217x; 1.0217x over previous
//
#include <hip/hip_runtime.h>
#include <hip/hip_bf16.h>

#define D 128

// ---------------- setup kernels ----------------

__global__ void k_zero(int* __restrict__ p, int n) {
    int i = blockIdx.x * 256 + threadIdx.x;
    if (i < n) p[i] = 0;
}

__global__ void k_count(const int* __restrict__ dst, int* __restrict__ cnt, int e) {
    int i = blockIdx.x * 256 + threadIdx.x;
    if (i < e) atomicAdd(&cnt[dst[i]], 1);
}

__global__ void k_dinv(const int* __restrict__ cnt, float* __restrict__ dinv, int n) {
    int i = blockIdx.x * 256 + threadIdx.x;
    if (i < n) {
        float deg = (float)(cnt[i] + 2);   // +2 = improved self-loop weight
        dinv[i] = 1.0f / sqrtf(deg);
    }
}

// ---- hierarchical scan: A) per-block reduce, B) scan partials, C) rescan ----
// chunk = 512 elements per 256-thread block

__global__ __launch_bounds__(256) void k_scanA(const int* __restrict__ cnt,
                                               int* __restrict__ partials, int n) {
    __shared__ int s[256];
    int b = blockIdx.x, t = threadIdx.x;
    int i0 = b * 512 + t * 2;
    int v = 0;
    if (i0 < n) v += cnt[i0];
    if (i0 + 1 < n) v += cnt[i0 + 1];
    s[t] = v;
    __syncthreads();
    for (int off = 128; off > 0; off >>= 1) {
        if (t < off) s[t] += s[t + off];
        __syncthreads();
    }
    if (t == 0) partials[b] = s[0];
}

__global__ __launch_bounds__(512) void k_scanB(const int* __restrict__ partials,
                                               int* __restrict__ base,
                                               int* __restrict__ off_n, int nb) {
    __shared__ int s[512];
    int t = threadIdx.x;
    int v = (t < nb) ? partials[t] : 0;
    s[t] = v;
    __syncthreads();
    for (int off = 1; off < 512; off <<= 1) {
        int x = (t >= off) ? s[t - off] : 0;
        __syncthreads();
        s[t] += x;
        __syncthreads();
    }
    if (t < nb) base[t] = s[t] - v;          // exclusive
    if (t == nb - 1) off_n[0] = s[t];        // total = offsets[N]
}

__global__ __launch_bounds__(256) void k_scanC(const int* __restrict__ cnt,
                                               const int* __restrict__ base,
                                               int* __restrict__ offsets,
                                               int* __restrict__ cursor, int n) {
    __shared__ int s[256];
    int b = blockIdx.x, t = threadIdx.x;
    int i0 = b * 512 + t * 2;
    int v0 = (i0 < n) ? cnt[i0] : 0;
    int v1 = (i0 + 1 < n) ? cnt[i0 + 1] : 0;
    int sum = v0 + v1;
    s[t] = sum;
    __syncthreads();
    for (int off = 1; off < 256; off <<= 1) {
        int x = (t >= off) ? s[t - off] : 0;
        __syncthreads();
        s[t] += x;
        __syncthreads();
    }
    int excl = s[t] - sum + base[b];
    if (i0 < n) { offsets[i0] = excl; cursor[i0] = excl; }
    if (i0 + 1 < n) { offsets[i0 + 1] = excl + v0; cursor[i0 + 1] = excl + v0; }
}

// packed CSR entry: .x = src node, .y = bit-cast float norm
// single 8B scattered store per edge (was 2x 4B to separate arrays ->
// two dirty 64B lines per edge; this halves scattered-line traffic)
__global__ void k_fill(const int* __restrict__ src, const int* __restrict__ dst,
                       int* __restrict__ cursor, const float* __restrict__ dinv,
                       int2* __restrict__ csr, int e) {
    int i = blockIdx.x * 256 + threadIdx.x;
    if (i < e) {
        int s = src[i];
        int d = dst[i];
        int pos = atomicAdd(&cursor[d], 1);
        csr[pos] = make_int2(s, __float_as_int(dinv[s] * dinv[d]));
    }
}

// ---------------- matmul: O[r][c] = sum_k H[r][k] * W[k][c] ----------------
// register-staged prefetch: chunk kc+1's global loads issue before chunk kc's
// compute, so HBM latency hides under ~4096 cyc of FMA instead of stalling
// every chunk at the barrier.
__global__ __launch_bounds__(256) void k_matmul(const float* __restrict__ H,
                                                const float* __restrict__ W,
                                                float* __restrict__ O, int nrows) {
    __shared__ float Ws[32 * D];    // Ws[k][c]
    __shared__ float HsT[32 * 128]; // HsT[k][r]
    const int t = threadIdx.x;
    const int row0 = blockIdx.x * 128;
    const int tx = t & 15;    // col group (8 cols)
    const int ty = t >> 4;    // row group (8 rows)
    const int r_st = t & 127;
    const int kb = (t >> 7) * 16;   // 0 or 16
    const int gr = row0 + r_st;
    const bool grok = (gr < nrows);

    float acc[8][8];
#pragma unroll
    for (int i = 0; i < 8; i++)
#pragma unroll
        for (int j = 0; j < 8; j++) acc[i][j] = 0.0f;

    // staging registers for the next chunk (+32 VGPR)
    float4 w0, w1, w2, w3, h0, h1, h2, h3;

    {   // prologue: load chunk 0
        const float4* W4 = (const float4*)W;
        w0 = W4[t]; w1 = W4[t + 256]; w2 = W4[t + 512]; w3 = W4[t + 768];
        if (grok) {
            const float4* Hp = (const float4*)(H + (size_t)gr * D + kb);
            h0 = Hp[0]; h1 = Hp[1]; h2 = Hp[2]; h3 = Hp[3];
        } else {
            h0 = h1 = h2 = h3 = make_float4(0.f, 0.f, 0.f, 0.f);
        }
    }

    for (int kc = 0; kc < D; kc += 32) {
        // drain staged regs into LDS (compiler inserts the vmcnt wait here,
        // which by then has been covered by the previous chunk's compute)
        {
            float4* Ws4 = (float4*)Ws;
            Ws4[t] = w0; Ws4[t + 256] = w1; Ws4[t + 512] = w2; Ws4[t + 768] = w3;
            float vals[16];
            *(float4*)&vals[0]  = h0;
            *(float4*)&vals[4]  = h1;
            *(float4*)&vals[8]  = h2;
            *(float4*)&vals[12] = h3;
#pragma unroll
            for (int j = 0; j < 16; j++) HsT[(kb + j) * 128 + r_st] = vals[j];
        }
        __syncthreads();

        // issue next chunk's loads NOW; results unused until next iteration
        if (kc + 32 < D) {
            const float4* W4 = (const float4*)(W + (kc + 32) * D);
            w0 = W4[t]; w1 = W4[t + 256]; w2 = W4[t + 512]; w3 = W4[t + 768];
            if (grok) {
                const float4* Hp = (const float4*)(H + (size_t)gr * D + (kc + 32) + kb);
                h0 = Hp[0]; h1 = Hp[1]; h2 = Hp[2]; h3 = Hp[3];
            }
        }

#pragma unroll 8
        for (int k = 0; k < 32; k++) {
            float4 a0 = *(const float4*)&HsT[k * 128 + ty * 8];
            float4 a1 = *(const float4*)&HsT[k * 128 + ty * 8 + 4];
            float4 b0 = *(const float4*)&Ws[k * D + tx * 8];
            float4 b1 = *(const float4*)&Ws[k * D + tx * 8 + 4];
            float ar[8] = {a0.x, a0.y, a0.z, a0.w, a1.x, a1.y, a1.z, a1.w};
            float br[8] = {b0.x, b0.y, b0.z, b0.w, b1.x, b1.y, b1.z, b1.w};
#pragma unroll
            for (int i = 0; i < 8; i++)
#pragma unroll
                for (int j = 0; j < 8; j++) acc[i][j] += ar[i] * br[j];
        }
        __syncthreads();
    }
#pragma unroll
    for (int i = 0; i < 8; i++) {
        int gr2 = row0 + ty * 8 + i;
        if (gr2 < nrows) {
            float4* Op = (float4*)(O + (size_t)gr2 * D + tx * 8);
            Op[0] = make_float4(acc[i][0], acc[i][1], acc[i][2], acc[i][3]);
            Op[1] = make_float4(acc[i][4], acc[i][5], acc[i][6], acc[i][7]);
        }
    }
}

// ---------------- gather ----------------
// one wave per node; half-wave per edge (32 lanes x float4 = 512B row);
// packed int2 CSR: one 8B broadcast load per edge.
__global__ __launch_bounds__(256) void k_gather(const float* __restrict__ T,
                                                const int2* __restrict__ csr,
                                                const int* __restrict__ offsets,
                                                const float* __restrict__ dinv,
                                                const float* __restrict__ bias,
                                                float* __restrict__ O, int n) {
    int node = blockIdx.x * 4 + (threadIdx.x >> 6);
    if (node >= n) return;
    int lane = threadIdx.x & 63;
    int half = lane >> 5;            // 0 or 1
    int c = (lane & 31) << 2;        // col base (float4)
    const float* Tc = T + c;

    float ax = 0.f, ay = 0.f, az = 0.f, aw = 0.f;
    if (half == 0) {
        float di = dinv[node];
        float sw = 2.0f * di * di;
        float4 v = *(const float4*)(Tc + (size_t)node * D);
        ax = sw * v.x; ay = sw * v.y; az = sw * v.z; aw = sw * v.w;
    }

    int e = offsets[node];
    const int e1 = offsets[node + 1];

    // 8 edges per group: 4 independent dual-row loads
    for (; e + 8 <= e1; e += 8) {
        int2 p0 = csr[e + half];
        int2 p1 = csr[e + 2 + half];
        int2 p2 = csr[e + 4 + half];
        int2 p3 = csr[e + 6 + half];
        float4 v0 = *(const float4*)(Tc + (size_t)p0.x * D);
        float4 v1 = *(const float4*)(Tc + (size_t)p1.x * D);
        float4 v2 = *(const float4*)(Tc + (size_t)p2.x * D);
        float4 v3 = *(const float4*)(Tc + (size_t)p3.x * D);
        float w0 = __int_as_float(p0.y), w1 = __int_as_float(p1.y);
        float w2 = __int_as_float(p2.y), w3 = __int_as_float(p3.y);
        ax += w0 * v0.x; ay += w0 * v0.y; az += w0 * v0.z; aw += w0 * v0.w;
        ax += w1 * v1.x; ay += w1 * v1.y; az += w1 * v1.z; aw += w1 * v1.w;
        ax += w2 * v2.x; ay += w2 * v2.y; az += w2 * v2.z; aw += w2 * v2.w;
        ax += w3 * v3.x; ay += w3 * v3.y; az += w3 * v3.z; aw += w3 * v3.w;
    }
    // 2 edges at a time
    for (; e + 2 <= e1; e += 2) {
        int2 p0 = csr[e + half];
        float4 v0 = *(const float4*)(Tc + (size_t)p0.x * D);
        float w0 = __int_as_float(p0.y);
        ax += w0 * v0.x; ay += w0 * v0.y; az += w0 * v0.z; aw += w0 * v0.w;
    }
    // odd leftover: half 0 only
    if (e < e1 && half == 0) {
        int2 p0 = csr[e];
        float4 v0 = *(const float4*)(Tc + (size_t)p0.x * D);
        float w0 = __int_as_float(p0.y);
        ax += w0 * v0.x; ay += w0 * v0.y; az += w0 * v0.z; aw += w0 * v0.w;
    }

    // cross-half reduction
    ax += __shfl_xor(ax, 32, 64);
    ay += __shfl_xor(ay, 32, 64);
    az += __shfl_xor(az, 32, 64);
    aw += __shfl_xor(aw, 32, 64);

    if (half == 0) {
        const float4 b4 = *(const float4*)(bias + c);
        float4 r = make_float4(ax + b4.x, ay + b4.y, az + b4.z, aw + b4.w);
        *(float4*)(O + (size_t)node * D + c) = r;
    }
}

// ---------------- launch ----------------

extern "C" void kernel_launch(void* const* d_in, const int* in_sizes, int n_in,
                              void* d_out, int out_size, void* d_ws, size_t ws_size,
                              hipStream_t stream) {
    const float* x  = (const float*)d_in[0];
    const int*   ei = (const int*)d_in[1];
    const float* W1 = (const float*)d_in[2];
    const float* b1 = (const float*)d_in[3];
    const float* W2 = (const float*)d_in[4];
    const float* b2 = (const float*)d_in[5];
    const int N = in_sizes[0] / D;
    const int E = in_sizes[1] / 2;
    float* out = (float*)d_out;

    char* ws = (char*)d_ws;
    size_t woff = 0;
    auto alloc = [&](size_t bytes) -> void* {
        void* p = ws + woff;
        woff = (woff + bytes + 15) & ~(size_t)15;
        return p;
    };
    float* T        = (float*)alloc((size_t)N * D * sizeof(float));
    int*   cnt      = (int*)  alloc((size_t)N * sizeof(int));
    int*   offsets  = (int*)  alloc((size_t)(N + 1) * sizeof(int));
    int*   cursor   = (int*)  alloc((size_t)N * sizeof(int));
    float* dinv     = (float*)alloc((size_t)N * sizeof(float));
    int2*  csr      = (int2*) alloc((size_t)E * sizeof(int2));
    int*   partials = (int*)  alloc(1024 * sizeof(int));
    int*   base     = (int*)  alloc(1024 * sizeof(int));
    (void)ws_size; (void)n_in; (void)out_size;

    const int* e_src = ei;
    const int* e_dst = ei + E;
    const int NB = (N + 511) / 512;   // 196 <= 512

    k_zero<<<(N + 255) / 256, 256, 0, stream>>>(cnt, N);
    k_count<<<(E + 255) / 256, 256, 0, stream>>>(e_dst, cnt, E);
    k_dinv<<<(N + 255) / 256, 256, 0, stream>>>(cnt, dinv, N);
    k_scanA<<<NB, 256, 0, stream>>>(cnt, partials, N);
    k_scanB<<<1, 512, 0, stream>>>(partials, base, offsets + N, NB);
    k_scanC<<<NB, 256, 0, stream>>>(cnt, base, offsets, cursor, N);
    k_fill<<<(E + 255) / 256, 256, 0, stream>>>(e_src, e_dst, cursor, dinv,
                                                csr, E);

    const float* h = x;
    for (int l = 0; l < 5; l++) {
        const float* W = l ? W2 : W1;
        const float* b = l ? b2 : b1;
        k_matmul<<<(N + 127) / 128, 256, 0, stream>>>(h, W, T, N);
        k_gather<<<(N + 3) / 4, 256, 0, stream>>>(T, csr, offsets,
                                                  dinv, b, out, N);
        h = out;
    }
}

// Round 2
// 1017.722 us; speedup vs baseline: 1.1124x; 1.0888x over previous
//
#include <hip/hip_runtime.h>
#include <hip/hip_bf16.h>

#define D 128

// ---------------- setup kernels ----------------

__global__ void k_zero(int* __restrict__ p, int n) {
    int i = blockIdx.x * 256 + threadIdx.x;
    if (i < n) p[i] = 0;
}

__global__ void k_count(const int* __restrict__ dst, int* __restrict__ cnt, int e) {
    int i = blockIdx.x * 256 + threadIdx.x;
    if (i < e) atomicAdd(&cnt[dst[i]], 1);
}

__global__ void k_dinv(const int* __restrict__ cnt, float* __restrict__ dinv, int n) {
    int i = blockIdx.x * 256 + threadIdx.x;
    if (i < n) {
        float deg = (float)(cnt[i] + 2);   // +2 = improved self-loop weight
        dinv[i] = 1.0f / sqrtf(deg);
    }
}

// ---- hierarchical scan: A) per-block reduce, B) scan partials, C) rescan ----
// chunk = 512 elements per 256-thread block

__global__ __launch_bounds__(256) void k_scanA(const int* __restrict__ cnt,
                                               int* __restrict__ partials, int n) {
    __shared__ int s[256];
    int b = blockIdx.x, t = threadIdx.x;
    int i0 = b * 512 + t * 2;
    int v = 0;
    if (i0 < n) v += cnt[i0];
    if (i0 + 1 < n) v += cnt[i0 + 1];
    s[t] = v;
    __syncthreads();
    for (int off = 128; off > 0; off >>= 1) {
        if (t < off) s[t] += s[t + off];
        __syncthreads();
    }
    if (t == 0) partials[b] = s[0];
}

__global__ __launch_bounds__(512) void k_scanB(const int* __restrict__ partials,
                                               int* __restrict__ base,
                                               int* __restrict__ off_n, int nb) {
    __shared__ int s[512];
    int t = threadIdx.x;
    int v = (t < nb) ? partials[t] : 0;
    s[t] = v;
    __syncthreads();
    for (int off = 1; off < 512; off <<= 1) {
        int x = (t >= off) ? s[t - off] : 0;
        __syncthreads();
        s[t] += x;
        __syncthreads();
    }
    if (t < nb) base[t] = s[t] - v;          // exclusive
    if (t == nb - 1) off_n[0] = s[t];        // total = offsets[N]
}

__global__ __launch_bounds__(256) void k_scanC(const int* __restrict__ cnt,
                                               const int* __restrict__ base,
                                               int* __restrict__ offsets,
                                               int* __restrict__ cursor, int n) {
    __shared__ int s[256];
    int b = blockIdx.x, t = threadIdx.x;
    int i0 = b * 512 + t * 2;
    int v0 = (i0 < n) ? cnt[i0] : 0;
    int v1 = (i0 + 1 < n) ? cnt[i0 + 1] : 0;
    int sum = v0 + v1;
    s[t] = sum;
    __syncthreads();
    for (int off = 1; off < 256; off <<= 1) {
        int x = (t >= off) ? s[t - off] : 0;
        __syncthreads();
        s[t] += x;
        __syncthreads();
    }
    int excl = s[t] - sum + base[b];
    if (i0 < n) { offsets[i0] = excl; cursor[i0] = excl; }
    if (i0 + 1 < n) { offsets[i0 + 1] = excl + v0; cursor[i0 + 1] = excl + v0; }
}

// packed CSR entry: .x = src node, .y = bit-cast float norm
__global__ void k_fill(const int* __restrict__ src, const int* __restrict__ dst,
                       int* __restrict__ cursor, const float* __restrict__ dinv,
                       int2* __restrict__ csr, int e) {
    int i = blockIdx.x * 256 + threadIdx.x;
    if (i < e) {
        int s = src[i];
        int d = dst[i];
        int pos = atomicAdd(&cursor[d], 1);
        csr[pos] = make_int2(s, __float_as_int(dinv[s] * dinv[d]));
    }
}

// ---------------- bias-correction machinery (all tiny) ----------------
// out = (A^5 x) Wtot + sum_{j=0..3} (A^j 1)(b2 W2^j) + (A^4 1)(b1 W2^4)

__global__ void k_ones(float* __restrict__ p, int n) {
    int i = blockIdx.x * 256 + threadIdx.x;
    if (i < n) p[i] = 1.0f;
}

__global__ __launch_bounds__(128) void k_copy128(const float* __restrict__ src,
                                                 float* __restrict__ dst) {
    dst[threadIdx.x] = src[threadIdx.x];
}

// sparse matvec: vout = A vin (A = normalized adjacency incl. self-loops)
__global__ void k_spmv(const int2* __restrict__ csr, const int* __restrict__ offsets,
                       const float* __restrict__ dinv, const float* __restrict__ vin,
                       float* __restrict__ vout, int n) {
    int i = blockIdx.x * 256 + threadIdx.x;
    if (i < n) {
        float di = dinv[i];
        float acc = 2.0f * di * di * vin[i];
        int e1 = offsets[i + 1];
        for (int e = offsets[i]; e < e1; e++) {
            int2 p = csr[e];
            acc += __int_as_float(p.y) * vin[p.x];
        }
        vout[i] = acc;
    }
}

// row-vector x matrix: out[d] = sum_k in[k] * W[k][d]  (1 block, 128 thr)
__global__ __launch_bounds__(128) void k_vecmat(const float* __restrict__ in,
                                                const float* __restrict__ W,
                                                float* __restrict__ out) {
    __shared__ float s[128];
    int d = threadIdx.x;
    s[d] = in[d];
    __syncthreads();
    float acc = 0.0f;
#pragma unroll 8
    for (int k = 0; k < 128; k++) acc += s[k] * W[k * 128 + d];
    out[d] = acc;
}

// small 128x128 @ 128x128: C[r][d] = sum_k A[r][k] B[k][d] (grid 128, 128 thr)
__global__ __launch_bounds__(128) void k_wmm(const float* __restrict__ A,
                                             const float* __restrict__ B,
                                             float* __restrict__ Cm) {
    __shared__ float a[128];
    int r = blockIdx.x, d = threadIdx.x;
    a[d] = A[r * 128 + d];
    __syncthreads();
    float acc = 0.0f;
#pragma unroll 8
    for (int k = 0; k < 128; k++) acc += a[k] * B[k * 128 + d];
    Cm[r * 128 + d] = acc;
}

// ---------------- matmul: O = H @ W + U C  (rank-5 correction) -------------
// register-staged prefetch: chunk kc+1's global loads issue before chunk kc's
// compute, so HBM latency hides under ~4096 cyc of FMA.
__global__ __launch_bounds__(256) void k_matmul(const float* __restrict__ H,
                                                const float* __restrict__ W,
                                                float* __restrict__ O,
                                                const float* __restrict__ ucol,  // [5][nrows]
                                                const float* __restrict__ cmat,  // [5][128]
                                                int nrows) {
    __shared__ float Ws[32 * D];    // Ws[k][c]
    __shared__ float HsT[32 * 128]; // HsT[k][r]
    const int t = threadIdx.x;
    const int row0 = blockIdx.x * 128;
    const int tx = t & 15;    // col group (8 cols)
    const int ty = t >> 4;    // row group (8 rows)
    const int r_st = t & 127;
    const int kb = (t >> 7) * 16;   // 0 or 16
    const int gr = row0 + r_st;
    const bool grok = (gr < nrows);

    float acc[8][8];
#pragma unroll
    for (int i = 0; i < 8; i++)
#pragma unroll
        for (int j = 0; j < 8; j++) acc[i][j] = 0.0f;

    // rank-5 bias correction folded into accumulator init (transient regs)
#pragma unroll
    for (int tt = 0; tt < 5; tt++) {
        float c0 = cmat[tt * D + tx * 8 + 0], c1 = cmat[tt * D + tx * 8 + 1];
        float c2 = cmat[tt * D + tx * 8 + 2], c3 = cmat[tt * D + tx * 8 + 3];
        float c4 = cmat[tt * D + tx * 8 + 4], c5 = cmat[tt * D + tx * 8 + 5];
        float c6 = cmat[tt * D + tx * 8 + 6], c7 = cmat[tt * D + tx * 8 + 7];
#pragma unroll
        for (int i = 0; i < 8; i++) {
            int gr2 = row0 + ty * 8 + i;
            if (gr2 < nrows) {
                float ut = ucol[(size_t)tt * nrows + gr2];
                acc[i][0] += ut * c0; acc[i][1] += ut * c1;
                acc[i][2] += ut * c2; acc[i][3] += ut * c3;
                acc[i][4] += ut * c4; acc[i][5] += ut * c5;
                acc[i][6] += ut * c6; acc[i][7] += ut * c7;
            }
        }
    }

    // staging registers for the next chunk
    float4 w0, w1, w2, w3, h0, h1, h2, h3;

    {   // prologue: load chunk 0
        const float4* W4 = (const float4*)W;
        w0 = W4[t]; w1 = W4[t + 256]; w2 = W4[t + 512]; w3 = W4[t + 768];
        if (grok) {
            const float4* Hp = (const float4*)(H + (size_t)gr * D + kb);
            h0 = Hp[0]; h1 = Hp[1]; h2 = Hp[2]; h3 = Hp[3];
        } else {
            h0 = h1 = h2 = h3 = make_float4(0.f, 0.f, 0.f, 0.f);
        }
    }

    for (int kc = 0; kc < D; kc += 32) {
        {
            float4* Ws4 = (float4*)Ws;
            Ws4[t] = w0; Ws4[t + 256] = w1; Ws4[t + 512] = w2; Ws4[t + 768] = w3;
            float vals[16];
            *(float4*)&vals[0]  = h0;
            *(float4*)&vals[4]  = h1;
            *(float4*)&vals[8]  = h2;
            *(float4*)&vals[12] = h3;
#pragma unroll
            for (int j = 0; j < 16; j++) HsT[(kb + j) * 128 + r_st] = vals[j];
        }
        __syncthreads();

        if (kc + 32 < D) {
            const float4* W4 = (const float4*)(W + (kc + 32) * D);
            w0 = W4[t]; w1 = W4[t + 256]; w2 = W4[t + 512]; w3 = W4[t + 768];
            if (grok) {
                const float4* Hp = (const float4*)(H + (size_t)gr * D + (kc + 32) + kb);
                h0 = Hp[0]; h1 = Hp[1]; h2 = Hp[2]; h3 = Hp[3];
            }
        }

#pragma unroll 8
        for (int k = 0; k < 32; k++) {
            float4 a0 = *(const float4*)&HsT[k * 128 + ty * 8];
            float4 a1 = *(const float4*)&HsT[k * 128 + ty * 8 + 4];
            float4 b0 = *(const float4*)&Ws[k * D + tx * 8];
            float4 b1 = *(const float4*)&Ws[k * D + tx * 8 + 4];
            float ar[8] = {a0.x, a0.y, a0.z, a0.w, a1.x, a1.y, a1.z, a1.w};
            float br[8] = {b0.x, b0.y, b0.z, b0.w, b1.x, b1.y, b1.z, b1.w};
#pragma unroll
            for (int i = 0; i < 8; i++)
#pragma unroll
                for (int j = 0; j < 8; j++) acc[i][j] += ar[i] * br[j];
        }
        __syncthreads();
    }
#pragma unroll
    for (int i = 0; i < 8; i++) {
        int gr2 = row0 + ty * 8 + i;
        if (gr2 < nrows) {
            float4* Op = (float4*)(O + (size_t)gr2 * D + tx * 8);
            Op[0] = make_float4(acc[i][0], acc[i][1], acc[i][2], acc[i][3]);
            Op[1] = make_float4(acc[i][4], acc[i][5], acc[i][6], acc[i][7]);
        }
    }
}

// ---------------- gather: O = A T (no bias) ----------------
// one wave per node; half-wave per edge (32 lanes x float4 = 512B row)
__global__ __launch_bounds__(256) void k_gather(const float* __restrict__ T,
                                                const int2* __restrict__ csr,
                                                const int* __restrict__ offsets,
                                                const float* __restrict__ dinv,
                                                float* __restrict__ O, int n) {
    int node = blockIdx.x * 4 + (threadIdx.x >> 6);
    if (node >= n) return;
    int lane = threadIdx.x & 63;
    int half = lane >> 5;            // 0 or 1
    int c = (lane & 31) << 2;        // col base (float4)
    const float* Tc = T + c;

    float ax = 0.f, ay = 0.f, az = 0.f, aw = 0.f;
    if (half == 0) {
        float di = dinv[node];
        float sw = 2.0f * di * di;
        float4 v = *(const float4*)(Tc + (size_t)node * D);
        ax = sw * v.x; ay = sw * v.y; az = sw * v.z; aw = sw * v.w;
    }

    int e = offsets[node];
    const int e1 = offsets[node + 1];

    for (; e + 8 <= e1; e += 8) {
        int2 p0 = csr[e + half];
        int2 p1 = csr[e + 2 + half];
        int2 p2 = csr[e + 4 + half];
        int2 p3 = csr[e + 6 + half];
        float4 v0 = *(const float4*)(Tc + (size_t)p0.x * D);
        float4 v1 = *(const float4*)(Tc + (size_t)p1.x * D);
        float4 v2 = *(const float4*)(Tc + (size_t)p2.x * D);
        float4 v3 = *(const float4*)(Tc + (size_t)p3.x * D);
        float w0 = __int_as_float(p0.y), w1 = __int_as_float(p1.y);
        float w2 = __int_as_float(p2.y), w3 = __int_as_float(p3.y);
        ax += w0 * v0.x; ay += w0 * v0.y; az += w0 * v0.z; aw += w0 * v0.w;
        ax += w1 * v1.x; ay += w1 * v1.y; az += w1 * v1.z; aw += w1 * v1.w;
        ax += w2 * v2.x; ay += w2 * v2.y; az += w2 * v2.z; aw += w2 * v2.w;
        ax += w3 * v3.x; ay += w3 * v3.y; az += w3 * v3.z; aw += w3 * v3.w;
    }
    for (; e + 2 <= e1; e += 2) {
        int2 p0 = csr[e + half];
        float4 v0 = *(const float4*)(Tc + (size_t)p0.x * D);
        float w0 = __int_as_float(p0.y);
        ax += w0 * v0.x; ay += w0 * v0.y; az += w0 * v0.z; aw += w0 * v0.w;
    }
    if (e < e1 && half == 0) {
        int2 p0 = csr[e];
        float4 v0 = *(const float4*)(Tc + (size_t)p0.x * D);
        float w0 = __int_as_float(p0.y);
        ax += w0 * v0.x; ay += w0 * v0.y; az += w0 * v0.z; aw += w0 * v0.w;
    }

    ax += __shfl_xor(ax, 32, 64);
    ay += __shfl_xor(ay, 32, 64);
    az += __shfl_xor(az, 32, 64);
    aw += __shfl_xor(aw, 32, 64);

    if (half == 0) {
        *(float4*)(O + (size_t)node * D + c) = make_float4(ax, ay, az, aw);
    }
}

// ---------------- launch ----------------
// Algebraic restructuring: the whole net is linear, so
//   out = (A^5 x)(W1 W2^4) + (A^4 1)(b1 W2^4) + sum_{j=0..3}(A^j 1)(b2 W2^j)
// => 5 gathers on raw features + ONE dense matmul (was 5+5).

extern "C" void kernel_launch(void* const* d_in, const int* in_sizes, int n_in,
                              void* d_out, int out_size, void* d_ws, size_t ws_size,
                              hipStream_t stream) {
    const float* x  = (const float*)d_in[0];
    const int*   ei = (const int*)d_in[1];
    const float* W1 = (const float*)d_in[2];
    const float* b1 = (const float*)d_in[3];
    const float* W2 = (const float*)d_in[4];
    const float* b2 = (const float*)d_in[5];
    const int N = in_sizes[0] / D;
    const int E = in_sizes[1] / 2;
    float* out = (float*)d_out;

    char* ws = (char*)d_ws;
    size_t woff = 0;
    auto alloc = [&](size_t bytes) -> void* {
        void* p = ws + woff;
        woff = (woff + bytes + 15) & ~(size_t)15;
        return p;
    };
    float* T        = (float*)alloc((size_t)N * D * sizeof(float));
    int*   cnt      = (int*)  alloc((size_t)N * sizeof(int));
    int*   offsets  = (int*)  alloc((size_t)(N + 1) * sizeof(int));
    int*   cursor   = (int*)  alloc((size_t)N * sizeof(int));
    float* dinv     = (float*)alloc((size_t)N * sizeof(float));
    int2*  csr      = (int2*) alloc((size_t)E * sizeof(int2));
    int*   partials = (int*)  alloc(1024 * sizeof(int));
    int*   base     = (int*)  alloc(1024 * sizeof(int));
    float* ucol     = (float*)alloc((size_t)5 * N * sizeof(float));   // [5][N]: A^j 1
    float* cmat     = (float*)alloc(5 * 128 * sizeof(float));         // [5][128]
    float* rbuf     = (float*)alloc(2 * 128 * sizeof(float));
    float* Wa       = (float*)alloc(128 * 128 * sizeof(float));
    float* Wb       = (float*)alloc(128 * 128 * sizeof(float));
    (void)ws_size; (void)n_in; (void)out_size;

    const int* e_src = ei;
    const int* e_dst = ei + E;
    const int NB = (N + 511) / 512;

    // --- CSR build ---
    k_zero<<<(N + 255) / 256, 256, 0, stream>>>(cnt, N);
    k_count<<<(E + 255) / 256, 256, 0, stream>>>(e_dst, cnt, E);
    k_dinv<<<(N + 255) / 256, 256, 0, stream>>>(cnt, dinv, N);
    k_scanA<<<NB, 256, 0, stream>>>(cnt, partials, N);
    k_scanB<<<1, 512, 0, stream>>>(partials, base, offsets + N, NB);
    k_scanC<<<NB, 256, 0, stream>>>(cnt, base, offsets, cursor, N);
    k_fill<<<(E + 255) / 256, 256, 0, stream>>>(e_src, e_dst, cursor, dinv, csr, E);

    // --- weight chain: Wtot = W1 W2^4 (Wb holds result) ---
    k_wmm<<<128, 128, 0, stream>>>(W1, W2, Wa);
    k_wmm<<<128, 128, 0, stream>>>(Wa, W2, Wb);
    k_wmm<<<128, 128, 0, stream>>>(Wb, W2, Wa);
    k_wmm<<<128, 128, 0, stream>>>(Wa, W2, Wb);

    // --- bias row-vectors: cmat rows 0..3 = b2 W2^j (j=0..3), row 4 = b1 W2^4 ---
    k_copy128<<<1, 128, 0, stream>>>(b2, cmat);
    k_vecmat<<<1, 128, 0, stream>>>(cmat,           W2, cmat + 128);
    k_vecmat<<<1, 128, 0, stream>>>(cmat + 128,     W2, cmat + 256);
    k_vecmat<<<1, 128, 0, stream>>>(cmat + 256,     W2, cmat + 384);
    k_copy128<<<1, 128, 0, stream>>>(b1, rbuf);
    k_vecmat<<<1, 128, 0, stream>>>(rbuf,       W2, rbuf + 128);
    k_vecmat<<<1, 128, 0, stream>>>(rbuf + 128, W2, rbuf);
    k_vecmat<<<1, 128, 0, stream>>>(rbuf,       W2, rbuf + 128);
    k_vecmat<<<1, 128, 0, stream>>>(rbuf + 128, W2, cmat + 512);

    // --- degree vectors: ucol rows = A^j 1, j=0..4 ---
    k_ones<<<(N + 255) / 256, 256, 0, stream>>>(ucol, N);
    k_spmv<<<(N + 255) / 256, 256, 0, stream>>>(csr, offsets, dinv, ucol,         ucol + N,     N);
    k_spmv<<<(N + 255) / 256, 256, 0, stream>>>(csr, offsets, dinv, ucol + N,     ucol + 2 * N, N);
    k_spmv<<<(N + 255) / 256, 256, 0, stream>>>(csr, offsets, dinv, ucol + 2 * N, ucol + 3 * N, N);
    k_spmv<<<(N + 255) / 256, 256, 0, stream>>>(csr, offsets, dinv, ucol + 3 * N, ucol + 4 * N, N);

    // --- g = A^5 x, ping-pong T <-> out ---
    const int GG = (N + 3) / 4;
    k_gather<<<GG, 256, 0, stream>>>(x,   csr, offsets, dinv, T,   N);
    k_gather<<<GG, 256, 0, stream>>>(T,   csr, offsets, dinv, out, N);
    k_gather<<<GG, 256, 0, stream>>>(out, csr, offsets, dinv, T,   N);
    k_gather<<<GG, 256, 0, stream>>>(T,   csr, offsets, dinv, out, N);
    k_gather<<<GG, 256, 0, stream>>>(out, csr, offsets, dinv, T,   N);

    // --- out = T @ Wtot + U C ---
    k_matmul<<<(N + 127) / 128, 256, 0, stream>>>(T, Wb, out, ucol, cmat, N);
}